// Round 15
// baseline (1411.526 us; speedup 1.0000x reference)
//
#include <hip/hip_runtime.h>
#include <hip/hip_bf16.h>

#define NN 16384
#define NE 65536
#define NESL (NE + NN)
#define NG 64

typedef __hip_bfloat16 bf16;
typedef __attribute__((ext_vector_type(8))) short short8v;
typedef __attribute__((ext_vector_type(4))) short short4v;
typedef __attribute__((ext_vector_type(4))) float f32x4;
typedef __attribute__((address_space(3))) void lds_void;
typedef const __attribute__((address_space(1))) void glb_void;

__device__ __forceinline__ short bfbits(float v) {
  bf16 h = __float2bfloat16(v);
  return *(short*)&h;
}
__device__ __forceinline__ float bfs2f(short s) {
  return __uint_as_float(((unsigned)(unsigned short)s) << 16);
}
__device__ __forceinline__ void gld16(const void* g, void* l) {
  __builtin_amdgcn_global_load_lds((glb_void*)g, (lds_void*)l, 16, 0, 0);
}

// ---------------- utility ----------------
__global__ void k_zero2(int* a, int* b, int n) {
  int i = blockIdx.x * blockDim.x + threadIdx.x;
  if (i < n) { a[i] = 0; b[i] = 0; }
}

// ---------------- graph preprocessing ----------------

__global__ void k_ranges(const int* __restrict__ batch, int* __restrict__ R,
                         float* __restrict__ cnt) {
  int g = threadIdx.x;
  if (g <= NG) {
    int lo = 0, hi = NN;
    while (lo < hi) { int mid = (lo + hi) >> 1; if (batch[mid] < g) lo = mid + 1; else hi = mid; }
    R[g] = lo;
  }
  __syncthreads();
  if (g < NG) cnt[g] = fmaxf((float)(R[g + 1] - R[g]), 1.0f);
}

__global__ void k_deg(const int* __restrict__ dst, int* __restrict__ deg) {
  int e = blockIdx.x * blockDim.x + threadIdx.x;
  if (e < NE) atomicAdd(deg + dst[e], 1);
}

__global__ void k_dis(const int* __restrict__ deg, float* __restrict__ dis) {
  int n = blockIdx.x * blockDim.x + threadIdx.x;
  if (n < NN) { int d = deg[n]; dis[n] = d > 0 ? 1.0f / sqrtf((float)d) : 0.0f; }
}

__global__ void k_scan(const int* __restrict__ deg, int* __restrict__ rowptr) {
  __shared__ int sums[1024];
  int tid = threadIdx.x;
  int base = tid * 16;
  int loc[16];
  int run = 0;
#pragma unroll
  for (int i = 0; i < 16; i++) { run += deg[base + i] + 1; loc[i] = run; }
  sums[tid] = run;
  __syncthreads();
  for (int off = 1; off < 1024; off <<= 1) {
    int v = sums[tid];
    int u = (tid >= off) ? sums[tid - off] : 0;
    __syncthreads();
    sums[tid] = v + u;
    __syncthreads();
  }
  int offset = (tid > 0) ? sums[tid - 1] : 0;
  if (tid == 0) rowptr[0] = 0;
#pragma unroll
  for (int i = 0; i < 16; i++) rowptr[base + i + 1] = loc[i] + offset;
}

// CSR fill: srck = source node per CSR slot, normk = gcn norm (0 for self-loops)
__global__ void k_fill(const int* __restrict__ src, const int* __restrict__ dst,
                       const int* __restrict__ rowptr, const float* __restrict__ dis,
                       int* __restrict__ fill, int* __restrict__ srck,
                       float* __restrict__ normk) {
  int e = blockIdx.x * blockDim.x + threadIdx.x;
  if (e >= NESL) return;
  int s = e < NE ? src[e] : e - NE;
  int d = e < NE ? dst[e] : e - NE;
  int pos = rowptr[d] + atomicAdd(fill + d, 1);
  srck[pos] = s;
  normk[pos] = e < NE ? dis[s] * dis[d] : 0.0f;
}

// ---------------- packed split-bf16 weight prep ----------------
// Packed tile (128 cols x 32 k, 4096 shorts): FRAGMENT-LINEAR.
__global__ void k_wsplit2(const float* __restrict__ wa, const float* __restrict__ wb,
                          short* __restrict__ hi, short* __restrict__ lo, int K, int Nw) {
  int gi = blockIdx.x * blockDim.x + threadIdx.x;
  int ngroups = (Nw >> 6) * (K >> 5) * 512;
  if (gi >= ngroups) return;
  int g = gi & 511;
  int t = gi >> 9;
  int nkb = K >> 5;
  int tn = t / nkb, tk = t % nkb;
  int lane = g & 63;
  int n = tn * 128 + ((g >> 6) << 4) + (lane & 15);
  int kb = tk * 32 + ((lane >> 4) << 3);
  const float* w = (n < Nw) ? wa : wb;
  int nn = (n < Nw) ? n : n - Nw;
  short8v h, l;
#pragma unroll
  for (int j = 0; j < 8; j++) {
    float v = w[(size_t)(kb + j) * Nw + nn];
    short hb = bfbits(v);
    h[j] = hb;
    l[j] = bfbits(v - bfs2f(hb));
  }
  *(short8v*)(hi + (size_t)gi * 8) = h;
  *(short8v*)(lo + (size_t)gi * 8) = l;
}

// ---------------- MFMA GEMM 128x128 (3-deep pipelined) ----------
// COUT: 0 = f32, 1 = bf16, 2 = bf16 hi+lo planes (fp32-grade pair).
// Triple-buffered LDS: tile kb's loads get ~2 iterations to land.
// vmcnt constants: LPT = loads/wave/tile (SPLITA:8, else 6); wait 2*LPT in
// steady state (2 newer tiles in flight), LPT when 1 remains, 0 at the end.
template <int SPLITA, int COUT, int ACT>
__global__ __launch_bounds__(256) void gemm_mfma_p(const short* __restrict__ Ahi,
                                                   const short* __restrict__ Alo,
                                                   const short* __restrict__ Bthi,
                                                   const short* __restrict__ Btlo,
                                                   void* __restrict__ Cp,
                                                   short* __restrict__ Clo,
                                                   const float* __restrict__ bias,
                                                   int M, int N, int K) {
  __shared__ __align__(16) short sA[3][(SPLITA ? 2 : 1) * 4096];
  __shared__ __align__(16) short sB[3][8192];
  const int tid = threadIdx.x;
  const int wave = tid >> 6, lane = tid & 63;
  const int wm = wave >> 1, wn = wave & 1;
  const int nbx = gridDim.x;
  const int nwg = nbx * gridDim.y;
  const int hw = blockIdx.y * nbx + blockIdx.x;
  const int lg = (hw & 7) * (nwg >> 3) + (hw >> 3);
  const int row0 = (lg / nbx) * 128, col0 = (lg % nbx) * 128;
  const int nkb = K >> 5;
  const int c = wave * 2;
  const int ar = lane & 15, akc = lane >> 4;
  f32x4 acc[4][4] = {};

  auto stage = [&](int buf, int kb) {
    const short* bh = Bthi + ((size_t)(col0 >> 7) * nkb + kb) * 4096;
    const short* bl = Btlo + ((size_t)(col0 >> 7) * nkb + kb) * 4096;
    gld16(bh + (size_t)c * 512 + lane * 8, (char*)sB[buf] + c * 1024);
    gld16(bh + (size_t)(c + 1) * 512 + lane * 8, (char*)sB[buf] + (c + 1) * 1024);
    gld16(bl + (size_t)c * 512 + lane * 8, (char*)sB[buf] + 8192 + c * 1024);
    gld16(bl + (size_t)(c + 1) * 512 + lane * 8, (char*)sB[buf] + 8192 + (c + 1) * 1024);
    gld16(Ahi + (size_t)(row0 + c * 16 + ar) * K + kb * 32 + akc * 8,
          (char*)sA[buf] + c * 1024);
    gld16(Ahi + (size_t)(row0 + (c + 1) * 16 + ar) * K + kb * 32 + akc * 8,
          (char*)sA[buf] + (c + 1) * 1024);
    if constexpr (SPLITA) {
      gld16(Alo + (size_t)(row0 + c * 16 + ar) * K + kb * 32 + akc * 8,
            (char*)sA[buf] + 8192 + c * 1024);
      gld16(Alo + (size_t)(row0 + (c + 1) * 16 + ar) * K + kb * 32 + akc * 8,
            (char*)sA[buf] + 8192 + (c + 1) * 1024);
    }
  };

  stage(0, 0);
  if (nkb > 1) stage(1, 1);
  for (int kb = 0; kb < nkb; kb++) {
    int cur = kb % 3;
    if (kb + 2 < nkb) {
      stage((kb + 2) % 3, kb + 2);
      if constexpr (SPLITA)
        asm volatile("s_waitcnt vmcnt(16)" ::: "memory");
      else
        asm volatile("s_waitcnt vmcnt(12)" ::: "memory");
    } else if (kb + 1 < nkb) {
      if constexpr (SPLITA)
        asm volatile("s_waitcnt vmcnt(8)" ::: "memory");
      else
        asm volatile("s_waitcnt vmcnt(6)" ::: "memory");
    } else {
      asm volatile("s_waitcnt vmcnt(0)" ::: "memory");
    }
    __builtin_amdgcn_sched_barrier(0);
    __builtin_amdgcn_s_barrier();
    __builtin_amdgcn_sched_barrier(0);
    asm volatile("" ::: "memory");
    short8v af[4], al[4], bh[4], bl[4];
#pragma unroll
    for (int f = 0; f < 4; f++) {
      af[f] = *(short8v*)((char*)sA[cur] + (wm * 4 + f) * 1024 + lane * 16);
      if constexpr (SPLITA)
        al[f] = *(short8v*)((char*)sA[cur] + 8192 + (wm * 4 + f) * 1024 + lane * 16);
      bh[f] = *(short8v*)((char*)sB[cur] + (wn * 4 + f) * 1024 + lane * 16);
      bl[f] = *(short8v*)((char*)sB[cur] + 8192 + (wn * 4 + f) * 1024 + lane * 16);
    }
#pragma unroll
    for (int i = 0; i < 4; i++)
#pragma unroll
      for (int j = 0; j < 4; j++) {
        acc[i][j] = __builtin_amdgcn_mfma_f32_16x16x32_bf16(af[i], bh[j], acc[i][j], 0, 0, 0);
        acc[i][j] = __builtin_amdgcn_mfma_f32_16x16x32_bf16(af[i], bl[j], acc[i][j], 0, 0, 0);
        if constexpr (SPLITA)
          acc[i][j] = __builtin_amdgcn_mfma_f32_16x16x32_bf16(al[i], bh[j], acc[i][j], 0, 0, 0);
      }
    asm volatile("" ::: "memory");
    __builtin_amdgcn_sched_barrier(0);
    __builtin_amdgcn_s_barrier();
    __builtin_amdgcn_sched_barrier(0);
  }
#pragma unroll
  for (int i = 0; i < 4; i++)
#pragma unroll
    for (int j = 0; j < 4; j++)
#pragma unroll
      for (int r = 0; r < 4; r++) {
        int row = row0 + wm * 64 + i * 16 + ((lane >> 4) << 2) + r;
        int col = col0 + wn * 64 + j * 16 + (lane & 15);
        float v = acc[i][j][r];
        if (bias) v += bias[col];
        if constexpr (ACT == 1) v = v > 0.0f ? v : expf(v) - 1.0f;
        if constexpr (ACT == 2) v = fmaxf(v, 0.0f);
        if constexpr (COUT == 1) {
          ((short*)Cp)[(size_t)row * N + col] = bfbits(v);
        } else if constexpr (COUT == 2) {
          short hb = bfbits(v);
          ((short*)Cp)[(size_t)row * N + col] = hb;
          Clo[(size_t)row * N + col] = bfbits(v - bfs2f(hb));
        } else {
          ((float*)Cp)[(size_t)row * N + col] = v;
        }
      }
}

// ---------------- MFMA GEMM 256x128, 8 waves (non-split A, 2-deep) ---------
template <int CBF16, int ACT>
__global__ __launch_bounds__(512) void gemm_mfma_p256(const short* __restrict__ Ahi,
                                                      const short* __restrict__ Bthi,
                                                      const short* __restrict__ Btlo,
                                                      void* __restrict__ Cp,
                                                      const float* __restrict__ bias,
                                                      int M, int N, int K) {
  __shared__ __align__(16) short sA[2][8192];
  __shared__ __align__(16) short sB[2][8192];
  const int tid = threadIdx.x;
  const int wave = tid >> 6, lane = tid & 63;
  const int wm = wave >> 1, wn = wave & 1;
  const int nbx = gridDim.x;
  const int nwg = nbx * gridDim.y;
  const int hw = blockIdx.y * nbx + blockIdx.x;
  const int lg = (hw & 7) * (nwg >> 3) + (hw >> 3);
  const int row0 = (lg / nbx) * 256, col0 = (lg % nbx) * 128;
  const int nkb = K >> 5;
  const int ar = lane & 15, akc = lane >> 4;
  f32x4 acc[4][4] = {};

  auto stage = [&](int buf, int kb) {
    if (wave < 4) {
      const short* bh = Bthi + ((size_t)(col0 >> 7) * nkb + kb) * 4096;
      int cB = wave * 2;
      gld16(bh + (size_t)cB * 512 + lane * 8, (char*)sB[buf] + cB * 1024);
      gld16(bh + (size_t)(cB + 1) * 512 + lane * 8, (char*)sB[buf] + (cB + 1) * 1024);
    } else {
      const short* bl = Btlo + ((size_t)(col0 >> 7) * nkb + kb) * 4096;
      int cB = (wave - 4) * 2;
      gld16(bl + (size_t)cB * 512 + lane * 8, (char*)sB[buf] + 8192 + cB * 1024);
      gld16(bl + (size_t)(cB + 1) * 512 + lane * 8, (char*)sB[buf] + 8192 + (cB + 1) * 1024);
    }
    int cA = wave * 2;
    gld16(Ahi + (size_t)(row0 + cA * 16 + ar) * K + kb * 32 + akc * 8,
          (char*)sA[buf] + cA * 1024);
    gld16(Ahi + (size_t)(row0 + (cA + 1) * 16 + ar) * K + kb * 32 + akc * 8,
          (char*)sA[buf] + (cA + 1) * 1024);
  };

  stage(0, 0);
  for (int kb = 0; kb < nkb; kb++) {
    int cur = kb & 1;
    if (kb + 1 < nkb) {
      stage(cur ^ 1, kb + 1);
      asm volatile("s_waitcnt vmcnt(4)" ::: "memory");
    } else {
      asm volatile("s_waitcnt vmcnt(0)" ::: "memory");
    }
    __builtin_amdgcn_sched_barrier(0);
    __builtin_amdgcn_s_barrier();
    __builtin_amdgcn_sched_barrier(0);
    asm volatile("" ::: "memory");
    short8v af[4], bh[4], bl[4];
#pragma unroll
    for (int f = 0; f < 4; f++) {
      af[f] = *(short8v*)((char*)sA[cur] + (wm * 4 + f) * 1024 + lane * 16);
      bh[f] = *(short8v*)((char*)sB[cur] + (wn * 4 + f) * 1024 + lane * 16);
      bl[f] = *(short8v*)((char*)sB[cur] + 8192 + (wn * 4 + f) * 1024 + lane * 16);
    }
#pragma unroll
    for (int i = 0; i < 4; i++)
#pragma unroll
      for (int j = 0; j < 4; j++) {
        acc[i][j] = __builtin_amdgcn_mfma_f32_16x16x32_bf16(af[i], bh[j], acc[i][j], 0, 0, 0);
        acc[i][j] = __builtin_amdgcn_mfma_f32_16x16x32_bf16(af[i], bl[j], acc[i][j], 0, 0, 0);
      }
    asm volatile("" ::: "memory");
    __builtin_amdgcn_sched_barrier(0);
    __builtin_amdgcn_s_barrier();
    __builtin_amdgcn_sched_barrier(0);
  }
#pragma unroll
  for (int i = 0; i < 4; i++)
#pragma unroll
    for (int j = 0; j < 4; j++)
#pragma unroll
      for (int r = 0; r < 4; r++) {
        int row = row0 + wm * 64 + i * 16 + ((lane >> 4) << 2) + r;
        int col = col0 + wn * 64 + j * 16 + (lane & 15);
        float v = acc[i][j][r];
        if (bias) v += bias[col];
        if constexpr (ACT == 1) v = v > 0.0f ? v : expf(v) - 1.0f;
        if constexpr (ACT == 2) v = fmaxf(v, 0.0f);
        if constexpr (CBF16) {
          ((short*)Cp)[(size_t)row * N + col] = bfbits(v);
        } else {
          ((float*)Cp)[(size_t)row * N + col] = v;
        }
      }
}

// ---------------- GAT1 fused (rank-1) ----------------
__global__ void k_gat1_csr(const float* __restrict__ x, const float* __restrict__ wl,
                           const float* __restrict__ wr, const float* __restrict__ att,
                           const int* __restrict__ rowptr, const int* __restrict__ srck,
                           float* __restrict__ ework, const float* __restrict__ bias,
                           float* __restrict__ out) {
  int node = blockIdx.x * 4 + (threadIdx.x >> 6);
  int lane = threadIdx.x & 63;
  float wlv = wl[lane], wrv = wr[lane], av = att[lane];
  float xd = x[node];
  int beg = rowptr[node], end = rowptr[node + 1];
  float m = -INFINITY;
  for (int k = beg; k < end; k++) {
    float v = x[srck[k]] * wlv + xd * wrv;
    v = v > 0.0f ? v : 0.2f * v;
    float e = av * v;
#pragma unroll
    for (int off = 32; off; off >>= 1) e += __shfl_xor(e, off);
    if (lane == 0) ework[k] = e;
    m = fmaxf(m, e);
  }
  __syncthreads();
  float sum = 0.0f, agg = 0.0f;
  for (int k = beg + lane; k < end; k += 64) {
    float p = expf(ework[k] - m);
    sum += p;
    agg += p * x[srck[k]];
  }
#pragma unroll
  for (int off = 32; off; off >>= 1) {
    sum += __shfl_xor(sum, off);
    agg += __shfl_xor(agg, off);
  }
  float o = agg / (sum + 1e-16f) * wlv + bias[lane];
  out[(size_t)node * 64 + lane] = o > 0.0f ? o : expf(o) - 1.0f;
}

// ---------------- CSR per-node logits + softmax ----------------
template <int FO, int STR, typename XT>
__global__ void k_logits_csr(const XT* __restrict__ X, const float* __restrict__ att,
                             const int* __restrict__ rowptr, const int* __restrict__ srck,
                             float* __restrict__ pk, float* __restrict__ ssum) {
  int node = blockIdx.x * 4 + (threadIdx.x >> 6);
  int lane = threadIdx.x & 63;
  constexpr int NV = FO / 64;
  float xr[NV], at[NV];
  if constexpr (sizeof(XT) == 2) {
    const short* xrp = (const short*)X + (size_t)node * STR + FO;
#pragma unroll
    for (int j = 0; j < FO / 512; j++) {
      short8v v = *(const short8v*)(xrp + j * 512 + lane * 8);
      f32x4 a0 = *(const f32x4*)(att + j * 512 + lane * 8);
      f32x4 a1 = *(const f32x4*)(att + j * 512 + lane * 8 + 4);
#pragma unroll
      for (int t = 0; t < 8; t++) {
        xr[j * 8 + t] = bfs2f(v[t]);
        at[j * 8 + t] = t < 4 ? a0[t] : a1[t - 4];
      }
    }
  } else {
    const float* xrp = (const float*)X + (size_t)node * STR + FO;
#pragma unroll
    for (int j = 0; j < FO / 256; j++) {
      f32x4 v = *(const f32x4*)(xrp + j * 256 + lane * 4);
      f32x4 a = *(const f32x4*)(att + j * 256 + lane * 4);
#pragma unroll
      for (int t = 0; t < 4; t++) {
        xr[j * 4 + t] = v[t];
        at[j * 4 + t] = a[t];
      }
    }
  }
  int beg = rowptr[node], end = rowptr[node + 1];
  float m = -INFINITY;
  for (int k = beg; k < end; k++) {
    int s = srck[k];
    float acc = 0.0f;
    if constexpr (sizeof(XT) == 2) {
      const short* xlp = (const short*)X + (size_t)s * STR;
#pragma unroll
      for (int j = 0; j < FO / 512; j++) {
        short8v v = *(const short8v*)(xlp + j * 512 + lane * 8);
#pragma unroll
        for (int t = 0; t < 8; t++) {
          float u = bfs2f(v[t]) + xr[j * 8 + t];
          u = u > 0.0f ? u : 0.2f * u;
          acc += at[j * 8 + t] * u;
        }
      }
    } else {
      const float* xlp = (const float*)X + (size_t)s * STR;
#pragma unroll
      for (int j = 0; j < FO / 256; j++) {
        f32x4 v = *(const f32x4*)(xlp + j * 256 + lane * 4);
#pragma unroll
        for (int t = 0; t < 4; t++) {
          float u = v[t] + xr[j * 4 + t];
          u = u > 0.0f ? u : 0.2f * u;
          acc += at[j * 4 + t] * u;
        }
      }
    }
#pragma unroll
    for (int off = 32; off; off >>= 1) acc += __shfl_xor(acc, off);
    if (lane == 0) pk[k] = acc;
    m = fmaxf(m, acc);
  }
  __syncthreads();
  float sum = 0.0f;
  for (int k = beg + lane; k < end; k += 64) {
    float p = expf(pk[k] - m);
    pk[k] = p;
    sum += p;
  }
#pragma unroll
  for (int off = 32; off; off >>= 1) sum += __shfl_xor(sum, off);
  if (lane == 0) ssum[node] = sum;
}

// ---------------- gather-aggregation ----------------
template <int MODE, int SSTR, int OSTR>
__global__ void k_agg512(const float* __restrict__ Xsrc, const float* __restrict__ pk,
                         const float* __restrict__ ssum, const int* __restrict__ rowptr,
                         const int* __restrict__ srck, const float* __restrict__ normk,
                         const float* __restrict__ xwrb, const float* __restrict__ bias,
                         float* __restrict__ out, short* __restrict__ outhi,
                         short* __restrict__ outlo) {
  int wave = threadIdx.x >> 6;
  int node = blockIdx.x * 2 + (wave >> 1);
  int lane = threadIdx.x & 63;
  int c0 = (wave & 1) * 256 + lane * 4;
  f32x4 acc = {};
  int beg = rowptr[node], end = rowptr[node + 1];
  float inv = (MODE == 0) ? 1.0f / (ssum[node] + 1e-16f) : 1.0f;
  for (int k = beg; k < end; k++) {
    int s = srck[k];
    float w = (MODE == 0) ? pk[k] * inv : normk[k];
    f32x4 v = *(const f32x4*)(Xsrc + (size_t)s * SSTR + c0);
#pragma unroll
    for (int t = 0; t < 4; t++) acc[t] += w * v[t];
  }
  if constexpr (MODE == 1) {
    f32x4 xv = *(const f32x4*)(xwrb + (size_t)node * SSTR + 512 + c0);
#pragma unroll
    for (int t = 0; t < 4; t++) acc[t] = fmaxf(acc[t] + xv[t] + bias[c0 + t], 0.0f);
    *(f32x4*)(out + (size_t)node * OSTR + c0) = acc;
  } else {
    short4v hh, ll;
#pragma unroll
    for (int t = 0; t < 4; t++) {
      hh[t] = bfbits(acc[t]);
      ll[t] = bfbits(acc[t] - bfs2f(hh[t]));
    }
    *(short4v*)(outhi + (size_t)node * OSTR + c0) = hh;
    *(short4v*)(outlo + (size_t)node * OSTR + c0) = ll;
  }
}

template <int MODE, int SSTR, int XOFF>
__global__ void k_agg64(const float* __restrict__ Xsrc, const float* __restrict__ pk,
                        const float* __restrict__ ssum, const int* __restrict__ rowptr,
                        const int* __restrict__ srck, const float* __restrict__ normk,
                        const float* __restrict__ xwrb, const float* __restrict__ bias,
                        float* __restrict__ out, short* __restrict__ outhi,
                        short* __restrict__ outlo) {
  int node = blockIdx.x * (blockDim.x >> 6) + (threadIdx.x >> 6);
  if (node >= NN) return;
  int lane = threadIdx.x & 63;
  int cg = lane & 15, eg = lane >> 4;
  int c0 = cg * 4;
  f32x4 acc = {};
  int beg = rowptr[node], end = rowptr[node + 1];
  float inv = (MODE == 0) ? 1.0f / (ssum[node] + 1e-16f) : 1.0f;
  for (int k = beg + eg; k < end; k += 4) {
    int s = srck[k];
    float w = (MODE == 0) ? pk[k] * inv : normk[k];
    f32x4 v = *(const f32x4*)(Xsrc + (size_t)s * SSTR + c0);
#pragma unroll
    for (int t = 0; t < 4; t++) acc[t] += w * v[t];
  }
#pragma unroll
  for (int t = 0; t < 4; t++) {
    acc[t] += __shfl_xor(acc[t], 16);
    acc[t] += __shfl_xor(acc[t], 32);
  }
  if (eg == 0) {
    if constexpr (MODE == 1) {
      f32x4 xv = *(const f32x4*)(xwrb + (size_t)node * SSTR + XOFF + c0);
#pragma unroll
      for (int t = 0; t < 4; t++) acc[t] = fmaxf(acc[t] + xv[t] + bias[c0 + t], 0.0f);
      *(f32x4*)(out + (size_t)node * 64 + c0) = acc;
    } else {
      short4v hh, ll;
#pragma unroll
      for (int t = 0; t < 4; t++) {
        hh[t] = bfbits(acc[t]);
        ll[t] = bfbits(acc[t] - bfs2f(hh[t]));
      }
      *(short4v*)(outhi + (size_t)node * 64 + c0) = hh;
      *(short4v*)(outlo + (size_t)node * 64 + c0) = ll;
    }
  }
}

// ---------------- GraphNorm (vectorized, row-split partial stats) ----------
template <typename T, int VEC>
__global__ void k_gn_stats_v(const T* __restrict__ x, const int* __restrict__ R, int C,
                             float* __restrict__ s1p, float* __restrict__ s2p) {
  int g = blockIdx.x;
  int rs = blockIdx.y;
  int RS = gridDim.y;
  int c0 = threadIdx.x * VEC;
  if (c0 >= C) return;
  int beg = R[g], end = R[g + 1];
  int len = end - beg;
  int lo = beg + (int)(((long long)len * rs) / RS);
  int hi2 = beg + (int)(((long long)len * (rs + 1)) / RS);
  float a[VEC] = {}, b[VEC] = {};
  for (int n = lo; n < hi2; n++) {
    const T* p = x + (size_t)n * C + c0;
    float v[VEC];
    if constexpr (sizeof(T) == 2) {
      short8v h = *(const short8v*)p;
#pragma unroll
      for (int t = 0; t < VEC; t++) v[t] = bfs2f(h[t]);
    } else {
      f32x4 h = *(const f32x4*)p;
#pragma unroll
      for (int t = 0; t < VEC; t++) v[t] = h[t];
    }
#pragma unroll
    for (int t = 0; t < VEC; t++) {
      a[t] += v[t];
      b[t] += v[t] * v[t];
    }
  }
#pragma unroll
  for (int t = 0; t < VEC; t++) {
    s1p[((size_t)rs * NG + g) * C + c0 + t] = a[t];
    s2p[((size_t)rs * NG + g) * C + c0 + t] = b[t];
  }
}

// pair-plane stats: value = hi + lo (fp32-grade)
__global__ void k_gn_stats_pair(const short* __restrict__ xhi, const short* __restrict__ xlo,
                                const int* __restrict__ R, int C, float* __restrict__ s1p,
                                float* __restrict__ s2p) {
  int g = blockIdx.x;
  int rs = blockIdx.y;
  int RS = gridDim.y;
  int c0 = threadIdx.x * 8;
  if (c0 >= C) return;
  int beg = R[g], end = R[g + 1];
  int len = end - beg;
  int lo = beg + (int)(((long long)len * rs) / RS);
  int hi2 = beg + (int)(((long long)len * (rs + 1)) / RS);
  float a[8] = {}, b[8] = {};
  for (int n = lo; n < hi2; n++) {
    short8v h = *(const short8v*)(xhi + (size_t)n * C + c0);
    short8v l = *(const short8v*)(xlo + (size_t)n * C + c0);
#pragma unroll
    for (int t = 0; t < 8; t++) {
      float v = bfs2f(h[t]) + bfs2f(l[t]);
      a[t] += v;
      b[t] += v * v;
    }
  }
#pragma unroll
  for (int t = 0; t < 8; t++) {
    s1p[((size_t)rs * NG + g) * C + c0 + t] = a[t];
    s2p[((size_t)rs * NG + g) * C + c0 + t] = b[t];
  }
}

// ---------------- GN coefficient precompute: scale/shift per (g,c) --------
__global__ void k_gn_coef(const float* __restrict__ s1p, const float* __restrict__ s2p,
                          const float* __restrict__ cnt, const float* __restrict__ w,
                          const float* __restrict__ b, const float* __restrict__ ms, int C,
                          float* __restrict__ cs, float* __restrict__ cb) {
  int i = blockIdx.x * blockDim.x + threadIdx.x;
  if (i >= NG * C) return;
  int g = i / C, c = i % C;
  float sv1 = 0.0f, sv2 = 0.0f;
#pragma unroll
  for (int rs = 0; rs < 4; rs++) {
    sv1 += s1p[((size_t)rs * NG + g) * C + c];
    sv2 += s2p[((size_t)rs * NG + g) * C + c];
  }
  float ct = cnt[g];
  float mean = sv1 / ct;
  float mm = mean * ms[c];
  float var = sv2 / ct - 2.0f * mm * mean + mm * mm;
  float inv = 1.0f / sqrtf(var + 1e-5f);
  float sc = inv * w[c];
  cs[i] = sc;
  cb[i] = b[c] - mm * sc;
}

// pair-plane apply (coef): read hi+lo, affine in fp32, write back hi+lo
__global__ void k_gn_apply_pair(short* __restrict__ xhi, short* __restrict__ xlo,
                                const int* __restrict__ batch,
                                const float* __restrict__ cs, const float* __restrict__ cb,
                                int C, int total_vec) {
  int i = blockIdx.x * blockDim.x + threadIdx.x;
  if (i >= total_vec) return;
  int cpv = C / 8;
  int n = i / cpv, c0 = (i % cpv) * 8;
  int g = batch[n];
  short8v h = *(const short8v*)(xhi + (size_t)n * C + c0);
  short8v l = *(const short8v*)(xlo + (size_t)n * C + c0);
  short8v ho, loo;
#pragma unroll
  for (int t = 0; t < 8; t++) {
    int cc = c0 + t;
    float v = bfs2f(h[t]) + bfs2f(l[t]);
    v = v * cs[(size_t)g * C + cc] + cb[(size_t)g * C + cc];
    short hb = bfbits(v);
    ho[t] = hb;
    loo[t] = bfbits(v - bfs2f(hb));
  }
  *(short8v*)(xhi + (size_t)n * C + c0) = ho;
  *(short8v*)(xlo + (size_t)n * C + c0) = loo;
}

// EMIT: 0 in-place only; 2 = + hi plane; 3 = + hi & lo planes (VEC=4)
template <typename T, int VEC, int EMIT>
__global__ void k_gn_apply_v(T* __restrict__ x, const int* __restrict__ batch,
                             const float* __restrict__ cs, const float* __restrict__ cb,
                             int C, int total_vec, short* __restrict__ hip,
                             short* __restrict__ lop) {
  int i = blockIdx.x * blockDim.x + threadIdx.x;
  if (i >= total_vec) return;
  int cpv = C / VEC;
  int n = i / cpv, c0 = (i % cpv) * VEC;
  int g = batch[n];
  T* p = x + (size_t)n * C + c0;
  float v[VEC];
  if constexpr (sizeof(T) == 2) {
    short8v h = *(const short8v*)p;
#pragma unroll
    for (int t = 0; t < VEC; t++) v[t] = bfs2f(h[t]);
  } else {
    f32x4 h = *(const f32x4*)p;
#pragma unroll
    for (int t = 0; t < VEC; t++) v[t] = h[t];
  }
#pragma unroll
  for (int t = 0; t < VEC; t++) {
    int cc = c0 + t;
    v[t] = v[t] * cs[(size_t)g * C + cc] + cb[(size_t)g * C + cc];
  }
  if constexpr (sizeof(T) == 2) {
    short8v h;
#pragma unroll
    for (int t = 0; t < VEC; t++) h[t] = bfbits(v[t]);
    *(short8v*)p = h;
  } else {
    f32x4 h;
#pragma unroll
    for (int t = 0; t < VEC; t++) h[t] = v[t];
    *(f32x4*)p = h;
  }
  if constexpr (EMIT == 2 || EMIT == 3) {
    short4v hh;
#pragma unroll
    for (int t = 0; t < VEC; t++) hh[t] = bfbits(v[t]);
    *(short4v*)(hip + (size_t)n * C + c0) = hh;
    if constexpr (EMIT == 3) {
      short4v ll;
#pragma unroll
      for (int t = 0; t < VEC; t++) ll[t] = bfbits(v[t] - bfs2f(hh[t]));
      *(short4v*)(lop + (size_t)n * C + c0) = ll;
    }
  }
}

// ---------------- pooling + final linear ----------------
__global__ void k_pool(const float* __restrict__ h, const int* __restrict__ R,
                       const float* __restrict__ cnt, const float* __restrict__ lw,
                       const float* __restrict__ lb, float* __restrict__ out) {
  int g = blockIdx.x;
  int c = threadIdx.x;  // 64
  int beg = R[g], end = R[g + 1];
  float mx = -INFINITY, sm = 0.0f;
  for (int n = beg; n < end; n++) {
    float v = h[(size_t)n * 64 + c];
    mx = fmaxf(mx, v);
    sm += v;
  }
  __shared__ float feat[192];
  feat[c] = mx;
  feat[64 + c] = sm / cnt[g];
  feat[128 + c] = sm;
  __syncthreads();
  if (c < 2) {
    float acc = lb[c];
    for (int j = 0; j < 192; j++) acc += feat[j] * lw[j * 2 + c];
    out[g * 2 + c] = acc;
  }
}

// ---------------- launch ----------------

extern "C" void kernel_launch(void* const* d_in, const int* in_sizes, int n_in,
                              void* d_out, int out_size, void* d_ws, size_t ws_size,
                              hipStream_t stream) {
  const float* x = (const float*)d_in[0];
  const int* ei = (const int*)d_in[1];
  const int* batch = (const int*)d_in[2];
  const float* g1wl = (const float*)d_in[3];
  const float* g1wr = (const float*)d_in[4];
  const float* g1att = (const float*)d_in[5];
  const float* g1b = (const float*)d_in[6];
  const float* g2wl = (const float*)d_in[7];
  const float* g2wr = (const float*)d_in[8];
  const float* g2att = (const float*)d_in[9];
  const float* g2b = (const float*)d_in[10];
  const float* g3wl = (const float*)d_in[11];
  const float* g3wr = (const float*)d_in[12];
  const float* g3att = (const float*)d_in[13];
  const float* g3b = (const float*)d_in[14];
  const float* gn1w = (const float*)d_in[15];
  const float* gn1b = (const float*)d_in[16];
  const float* gn1ms = (const float*)d_in[17];
  const float* gn2w = (const float*)d_in[18];
  const float* gn2b = (const float*)d_in[19];
  const float* gn2ms = (const float*)d_in[20];
  const float* gn3w = (const float*)d_in[21];
  const float* gn3b = (const float*)d_in[22];
  const float* gn3ms = (const float*)d_in[23];
  const float* gn4w = (const float*)d_in[24];
  const float* gn4b = (const float*)d_in[25];
  const float* gn4ms = (const float*)d_in[26];
  const float* gn5w = (const float*)d_in[27];
  const float* gn5b = (const float*)d_in[28];
  const float* gn5ms = (const float*)d_in[29];
  const float* a1wi = (const float*)d_in[30];
  const float* a1wr = (const float*)d_in[31];
  const float* a1b = (const float*)d_in[32];
  const float* a2wi = (const float*)d_in[33];
  const float* a2wr = (const float*)d_in[34];
  const float* a2b = (const float*)d_in[35];
  const float* linw = (const float*)d_in[36];
  const float* linb = (const float*)d_in[37];
  const int* srcp = ei;
  const int* dstp = ei + NE;
  float* out = (float*)d_out;

  float* ws = (float*)d_ws;
  size_t o = 0;
  auto alloc = [&](size_t nfloats) { float* p = ws + o; o += nfloats; return p; };
  float* BIG0f = alloc((size_t)NN * 1024);  // 64 MB
  float* BIG1f = alloc((size_t)NN * 1024);  // 64 MB
  float* B0 = alloc((size_t)NN * 512);      // 32 MB
  float* B1 = alloc((size_t)NN * 512);      // 32 MB
  float* h1 = alloc((size_t)NN * 64);
  float* S0 = alloc((size_t)NN * 64);
  float* S1 = alloc((size_t)NN * 64);
  float* S2 = alloc((size_t)NN * 64);
  float* pk = alloc(NESL);
  float* normk = alloc(NESL);
  float* ssum = alloc(NN);
  float* dis = alloc(NN);
  float* cnt = alloc(NG);
  float* s1 = alloc((size_t)4 * NG * 2048);
  float* s2 = alloc((size_t)4 * NG * 2048);
  float* coefS = alloc((size_t)NG * 2048);
  float* coefB = alloc((size_t)NG * 2048);
  short* WThi = (short*)alloc((size_t)4096 * 512 / 2);
  short* WTlo = (short*)alloc((size_t)4096 * 512 / 2);
  int* deg = (int*)alloc(NN);
  int* rowptr = (int*)alloc(NN + 1);
  int* fill = (int*)alloc(NN);
  int* srck = (int*)alloc(NESL);
  int* R = (int*)alloc(72);

  bf16* XLR3 = (bf16*)BIG0f;       // [NN][4096] bf16 (spans BIG0f+BIG1f)
  short* h3hi = (short*)BIG0f;     // [NN][2048] hi plane (after XLR3 dead)
  short* h3lo = (short*)BIG1f;     // [NN][2048] lo plane
  float* h4 = BIG1f;               // [NN][512] f32 (after ARMA1 GEMM consumed h3lo)
  short* h4hi = (short*)BIG0f;     // [NN][512] planes (after h3hi dead)
  short* h4lo = h4hi + (size_t)NN * 512;
  short* XLR2 = (short*)B0;        // [NN][1024] bf16
  float* h2 = B0;                  // [NN][512] f32 (after XLR2 dead)
  short* h2hi = (short*)B1;        // [NN][512] bf16 hi plane
  short* agg2hi = (short*)B1;      // [NN][512] planes (after h2hi dead)
  short* agg2lo = agg2hi + (size_t)NN * 512;
  float* TXW1 = B0;                // [t1|xwr1] [NN][1024] f32 (spans B0+B1)
  float* TXW2 = S0;                // [t2|xwr2] [NN][128] f32 (spans S0+S1)
  short* h1hi = (short*)S2;        // [NN][64] planes
  short* h1lo = h1hi + (size_t)NN * 64;
  short* aggShi = (short*)S0;      // [NN][64] planes
  short* aggSlo = aggShi + (size_t)NN * 64;
  float* h5 = S2;                  // [NN][64] f32 (after h1 planes dead)

  // ---- preprocessing ----
  k_zero2<<<NN / 256, 256, 0, stream>>>(deg, fill, NN);
  k_ranges<<<1, 128, 0, stream>>>(batch, R, cnt);
  k_deg<<<NE / 256, 256, 0, stream>>>(dstp, deg);
  k_scan<<<1, 1024, 0, stream>>>(deg, rowptr);
  k_dis<<<NN / 256, 256, 0, stream>>>(deg, dis);
  k_fill<<<(NESL + 255) / 256, 256, 0, stream>>>(srcp, dstp, rowptr, dis, fill, srck, normk);

  // ---- GAT1 (1 -> 64, rank-1, fused) ----
  k_gat1_csr<<<NN / 4, 256, 0, stream>>>(x, g1wl, g1wr, g1att, rowptr, srck, pk, g1b, h1);
  k_gn_stats_v<float, 4><<<dim3(NG, 4), 16, 0, stream>>>(h1, R, 64, s1, s2);
  k_gn_coef<<<(NG * 64 + 255) / 256, 256, 0, stream>>>(s1, s2, cnt, gn1w, gn1b, gn1ms, 64,
                                                       coefS, coefB);
  k_gn_apply_v<float, 4, 3><<<NN * 16 / 256, 256, 0, stream>>>(h1, batch, coefS, coefB, 64,
                                                               NN * 16, h1hi, h1lo);

  // ---- GAT2 (64 -> 512) ----
  k_wsplit2<<<8192 / 256, 256, 0, stream>>>(g2wl, g2wr, WThi, WTlo, 64, 512);
  gemm_mfma_p<1, 1, 0><<<dim3(8, 128), 256, 0, stream>>>(h1hi, h1lo, WThi, WTlo, XLR2, nullptr,
                                                         nullptr, NN, 1024, 64);
  k_logits_csr<512, 1024, bf16><<<NN / 4, 256, 0, stream>>>((const bf16*)XLR2, g2att, rowptr,
                                                            srck, pk, ssum);
  k_agg64<0, 64, 0><<<NN / 4, 256, 0, stream>>>(h1, pk, ssum, rowptr, srck, normk, nullptr,
                                                nullptr, nullptr, aggShi, aggSlo);
  gemm_mfma_p<1, 0, 1><<<dim3(4, 128), 256, 0, stream>>>(aggShi, aggSlo, WThi, WTlo, h2,
                                                         nullptr, g2b, NN, 512, 64);
  k_gn_stats_v<float, 4><<<dim3(NG, 4), 128, 0, stream>>>(h2, R, 512, s1, s2);
  k_gn_coef<<<(NG * 512 + 255) / 256, 256, 0, stream>>>(s1, s2, cnt, gn2w, gn2b, gn2ms, 512,
                                                        coefS, coefB);
  k_gn_apply_v<float, 4, 2><<<NN * 128 / 256, 256, 0, stream>>>(h2, batch, coefS, coefB, 512,
                                                                NN * 128, h2hi, nullptr);

  // ---- GAT3 (512 -> 2048) ----
  k_wsplit2<<<262144 / 256, 256, 0, stream>>>(g3wl, g3wr, WThi, WTlo, 512, 2048);
  gemm_mfma_p256<1, 0><<<dim3(32, 64), 512, 0, stream>>>(h2hi, WThi, WTlo, XLR3, nullptr, NN,
                                                         4096, 512);
  k_logits_csr<2048, 4096, bf16><<<NN / 4, 256, 0, stream>>>(XLR3, g3att, rowptr, srck, pk, ssum);
  k_agg512<0, 512, 512><<<NN / 2, 256, 0, stream>>>(h2, pk, ssum, rowptr, srck, normk, nullptr,
                                                    nullptr, nullptr, agg2hi, agg2lo);
  gemm_mfma_p<1, 2, 1><<<dim3(16, 128), 256, 0, stream>>>(agg2hi, agg2lo, WThi, WTlo, h3hi,
                                                          h3lo, g3b, NN, 2048, 512);
  k_gn_stats_pair<<<dim3(NG, 4), 256, 0, stream>>>(h3hi, h3lo, R, 2048, s1, s2);
  k_gn_coef<<<(NG * 2048 + 255) / 256, 256, 0, stream>>>(s1, s2, cnt, gn3w, gn3b, gn3ms, 2048,
                                                         coefS, coefB);
  k_gn_apply_pair<<<NN * 256 / 256, 256, 0, stream>>>(h3hi, h3lo, batch, coefS, coefB, 2048,
                                                      NN * 256);

  // ---- ARMA1 (2048 -> 512): SPLITA fp32-grade (h3 hi + lo planes) ----
  k_wsplit2<<<262144 / 256, 256, 0, stream>>>(a1wi, a1wr, WThi, WTlo, 2048, 512);
  gemm_mfma_p<1, 0, 0><<<dim3(8, 128), 256, 0, stream>>>(h3hi, h3lo, WThi, WTlo, TXW1, nullptr,
                                                         nullptr, NN, 1024, 2048);
  k_agg512<1, 1024, 512><<<NN / 2, 256, 0, stream>>>(TXW1, pk, nullptr, rowptr, srck, normk,
                                                     TXW1, a1b, h4, nullptr, nullptr);
  k_gn_stats_v<float, 4><<<dim3(NG, 4), 128, 0, stream>>>(h4, R, 512, s1, s2);
  k_gn_coef<<<(NG * 512 + 255) / 256, 256, 0, stream>>>(s1, s2, cnt, gn4w, gn4b, gn4ms, 512,
                                                        coefS, coefB);
  k_gn_apply_v<float, 4, 3><<<NN * 128 / 256, 256, 0, stream>>>(h4, batch, coefS, coefB, 512,
                                                                NN * 128, h4hi, h4lo);

  // ---- ARMA2 (512 -> 64) ----
  k_wsplit2<<<8192 / 256, 256, 0, stream>>>(a2wi, a2wr, WThi, WTlo, 512, 64);
  gemm_mfma_p<1, 0, 0><<<dim3(1, 128), 256, 0, stream>>>(h4hi, h4lo, WThi, WTlo, TXW2, nullptr,
                                                         nullptr, NN, 128, 512);
  k_agg64<1, 128, 64><<<NN / 4, 256, 0, stream>>>(TXW2, pk, nullptr, rowptr, srck, normk, TXW2,
                                                  a2b, h5, nullptr, nullptr);
  k_gn_stats_v<float, 4><<<dim3(NG, 4), 16, 0, stream>>>(h5, R, 64, s1, s2);
  k_gn_coef<<<(NG * 64 + 255) / 256, 256, 0, stream>>>(s1, s2, cnt, gn5w, gn5b, gn5ms, 64,
                                                       coefS, coefB);
  k_gn_apply_v<float, 4, 0><<<NN * 16 / 256, 256, 0, stream>>>(h5, batch, coefS, coefB, 64,
                                                               NN * 16, nullptr, nullptr);

  // ---- pooling + linear ----
  k_pool<<<NG, 64, 0, stream>>>(h5, R, cnt, linw, linb, out);
}

// Round 16
// 1081.600 us; speedup vs baseline: 1.3050x; 1.3050x over previous
//
#include <hip/hip_runtime.h>
#include <hip/hip_bf16.h>

#define NN 16384
#define NE 65536
#define NESL (NE + NN)
#define NG 64

typedef __hip_bfloat16 bf16;
typedef __attribute__((ext_vector_type(8))) short short8v;
typedef __attribute__((ext_vector_type(4))) short short4v;
typedef __attribute__((ext_vector_type(4))) float f32x4;
typedef __attribute__((address_space(3))) void lds_void;
typedef const __attribute__((address_space(1))) void glb_void;

__device__ __forceinline__ short bfbits(float v) {
  bf16 h = __float2bfloat16(v);
  return *(short*)&h;
}
__device__ __forceinline__ float bfs2f(short s) {
  return __uint_as_float(((unsigned)(unsigned short)s) << 16);
}
__device__ __forceinline__ void gld16(const void* g, void* l) {
  __builtin_amdgcn_global_load_lds((glb_void*)g, (lds_void*)l, 16, 0, 0);
}

// ---------------- utility ----------------
__global__ void k_zero2(int* a, int* b, int n) {
  int i = blockIdx.x * blockDim.x + threadIdx.x;
  if (i < n) { a[i] = 0; b[i] = 0; }
}

// ---------------- graph preprocessing ----------------

__global__ void k_ranges(const int* __restrict__ batch, int* __restrict__ R,
                         float* __restrict__ cnt) {
  int g = threadIdx.x;
  if (g <= NG) {
    int lo = 0, hi = NN;
    while (lo < hi) { int mid = (lo + hi) >> 1; if (batch[mid] < g) lo = mid + 1; else hi = mid; }
    R[g] = lo;
  }
  __syncthreads();
  if (g < NG) cnt[g] = fmaxf((float)(R[g + 1] - R[g]), 1.0f);
}

__global__ void k_deg(const int* __restrict__ dst, int* __restrict__ deg) {
  int e = blockIdx.x * blockDim.x + threadIdx.x;
  if (e < NE) atomicAdd(deg + dst[e], 1);
}

__global__ void k_dis(const int* __restrict__ deg, float* __restrict__ dis) {
  int n = blockIdx.x * blockDim.x + threadIdx.x;
  if (n < NN) { int d = deg[n]; dis[n] = d > 0 ? 1.0f / sqrtf((float)d) : 0.0f; }
}

__global__ void k_scan(const int* __restrict__ deg, int* __restrict__ rowptr) {
  __shared__ int sums[1024];
  int tid = threadIdx.x;
  int base = tid * 16;
  int loc[16];
  int run = 0;
#pragma unroll
  for (int i = 0; i < 16; i++) { run += deg[base + i] + 1; loc[i] = run; }
  sums[tid] = run;
  __syncthreads();
  for (int off = 1; off < 1024; off <<= 1) {
    int v = sums[tid];
    int u = (tid >= off) ? sums[tid - off] : 0;
    __syncthreads();
    sums[tid] = v + u;
    __syncthreads();
  }
  int offset = (tid > 0) ? sums[tid - 1] : 0;
  if (tid == 0) rowptr[0] = 0;
#pragma unroll
  for (int i = 0; i < 16; i++) rowptr[base + i + 1] = loc[i] + offset;
}

// CSR fill: srck = source node per CSR slot, normk = gcn norm (0 for self-loops)
__global__ void k_fill(const int* __restrict__ src, const int* __restrict__ dst,
                       const int* __restrict__ rowptr, const float* __restrict__ dis,
                       int* __restrict__ fill, int* __restrict__ srck,
                       float* __restrict__ normk) {
  int e = blockIdx.x * blockDim.x + threadIdx.x;
  if (e >= NESL) return;
  int s = e < NE ? src[e] : e - NE;
  int d = e < NE ? dst[e] : e - NE;
  int pos = rowptr[d] + atomicAdd(fill + d, 1);
  srck[pos] = s;
  normk[pos] = e < NE ? dis[s] * dis[d] : 0.0f;
}

// ---------------- packed split-bf16 weight prep ----------------
// Packed tile (128 cols x 32 k, 4096 shorts): FRAGMENT-LINEAR.
__global__ void k_wsplit2(const float* __restrict__ wa, const float* __restrict__ wb,
                          short* __restrict__ hi, short* __restrict__ lo, int K, int Nw) {
  int gi = blockIdx.x * blockDim.x + threadIdx.x;
  int ngroups = (Nw >> 6) * (K >> 5) * 512;
  if (gi >= ngroups) return;
  int g = gi & 511;
  int t = gi >> 9;
  int nkb = K >> 5;
  int tn = t / nkb, tk = t % nkb;
  int lane = g & 63;
  int n = tn * 128 + ((g >> 6) << 4) + (lane & 15);
  int kb = tk * 32 + ((lane >> 4) << 3);
  const float* w = (n < Nw) ? wa : wb;
  int nn = (n < Nw) ? n : n - Nw;
  short8v h, l;
#pragma unroll
  for (int j = 0; j < 8; j++) {
    float v = w[(size_t)(kb + j) * Nw + nn];
    short hb = bfbits(v);
    h[j] = hb;
    l[j] = bfbits(v - bfs2f(hb));
  }
  *(short8v*)(hi + (size_t)gi * 8) = h;
  *(short8v*)(lo + (size_t)gi * 8) = l;
}

// ---------------- MFMA GEMM 128x128 (2-phase pipelined, verified) ----------
// COUT: 0 = f32, 1 = bf16, 2 = bf16 hi+lo planes (fp32-grade pair).
template <int SPLITA, int COUT, int ACT>
__global__ __launch_bounds__(256) void gemm_mfma_p(const short* __restrict__ Ahi,
                                                   const short* __restrict__ Alo,
                                                   const short* __restrict__ Bthi,
                                                   const short* __restrict__ Btlo,
                                                   void* __restrict__ Cp,
                                                   short* __restrict__ Clo,
                                                   const float* __restrict__ bias,
                                                   int M, int N, int K) {
  __shared__ __align__(16) short sA[2][(SPLITA ? 2 : 1) * 4096];
  __shared__ __align__(16) short sB[2][8192];
  const int tid = threadIdx.x;
  const int wave = tid >> 6, lane = tid & 63;
  const int wm = wave >> 1, wn = wave & 1;
  const int nbx = gridDim.x;
  const int nwg = nbx * gridDim.y;
  const int hw = blockIdx.y * nbx + blockIdx.x;
  const int lg = (hw & 7) * (nwg >> 3) + (hw >> 3);
  const int row0 = (lg / nbx) * 128, col0 = (lg % nbx) * 128;
  const int nkb = K >> 5;
  const int c = wave * 2;
  const int ar = lane & 15, akc = lane >> 4;
  f32x4 acc[4][4] = {};

  auto stage = [&](int buf, int kb) {
    const short* bh = Bthi + ((size_t)(col0 >> 7) * nkb + kb) * 4096;
    const short* bl = Btlo + ((size_t)(col0 >> 7) * nkb + kb) * 4096;
    gld16(bh + (size_t)c * 512 + lane * 8, (char*)sB[buf] + c * 1024);
    gld16(bh + (size_t)(c + 1) * 512 + lane * 8, (char*)sB[buf] + (c + 1) * 1024);
    gld16(bl + (size_t)c * 512 + lane * 8, (char*)sB[buf] + 8192 + c * 1024);
    gld16(bl + (size_t)(c + 1) * 512 + lane * 8, (char*)sB[buf] + 8192 + (c + 1) * 1024);
    gld16(Ahi + (size_t)(row0 + c * 16 + ar) * K + kb * 32 + akc * 8,
          (char*)sA[buf] + c * 1024);
    gld16(Ahi + (size_t)(row0 + (c + 1) * 16 + ar) * K + kb * 32 + akc * 8,
          (char*)sA[buf] + (c + 1) * 1024);
    if constexpr (SPLITA) {
      gld16(Alo + (size_t)(row0 + c * 16 + ar) * K + kb * 32 + akc * 8,
            (char*)sA[buf] + 8192 + c * 1024);
      gld16(Alo + (size_t)(row0 + (c + 1) * 16 + ar) * K + kb * 32 + akc * 8,
            (char*)sA[buf] + 8192 + (c + 1) * 1024);
    }
  };

  stage(0, 0);
  for (int kb = 0; kb < nkb; kb++) {
    int cur = kb & 1;
    if (kb + 1 < nkb) {
      stage(cur ^ 1, kb + 1);
      if constexpr (SPLITA)
        asm volatile("s_waitcnt vmcnt(8)" ::: "memory");
      else
        asm volatile("s_waitcnt vmcnt(6)" ::: "memory");
    } else {
      asm volatile("s_waitcnt vmcnt(0)" ::: "memory");
    }
    __builtin_amdgcn_sched_barrier(0);
    __builtin_amdgcn_s_barrier();
    __builtin_amdgcn_sched_barrier(0);
    asm volatile("" ::: "memory");
    short8v af[4], al[4], bh[4], bl[4];
#pragma unroll
    for (int f = 0; f < 4; f++) {
      af[f] = *(short8v*)((char*)sA[cur] + (wm * 4 + f) * 1024 + lane * 16);
      if constexpr (SPLITA)
        al[f] = *(short8v*)((char*)sA[cur] + 8192 + (wm * 4 + f) * 1024 + lane * 16);
      bh[f] = *(short8v*)((char*)sB[cur] + (wn * 4 + f) * 1024 + lane * 16);
      bl[f] = *(short8v*)((char*)sB[cur] + 8192 + (wn * 4 + f) * 1024 + lane * 16);
    }
#pragma unroll
    for (int i = 0; i < 4; i++)
#pragma unroll
      for (int j = 0; j < 4; j++) {
        acc[i][j] = __builtin_amdgcn_mfma_f32_16x16x32_bf16(af[i], bh[j], acc[i][j], 0, 0, 0);
        acc[i][j] = __builtin_amdgcn_mfma_f32_16x16x32_bf16(af[i], bl[j], acc[i][j], 0, 0, 0);
        if constexpr (SPLITA)
          acc[i][j] = __builtin_amdgcn_mfma_f32_16x16x32_bf16(al[i], bh[j], acc[i][j], 0, 0, 0);
      }
    asm volatile("" ::: "memory");
    __builtin_amdgcn_sched_barrier(0);
    __builtin_amdgcn_s_barrier();
    __builtin_amdgcn_sched_barrier(0);
  }
#pragma unroll
  for (int i = 0; i < 4; i++)
#pragma unroll
    for (int j = 0; j < 4; j++)
#pragma unroll
      for (int r = 0; r < 4; r++) {
        int row = row0 + wm * 64 + i * 16 + ((lane >> 4) << 2) + r;
        int col = col0 + wn * 64 + j * 16 + (lane & 15);
        float v = acc[i][j][r];
        if (bias) v += bias[col];
        if constexpr (ACT == 1) v = v > 0.0f ? v : expf(v) - 1.0f;
        if constexpr (ACT == 2) v = fmaxf(v, 0.0f);
        if constexpr (COUT == 1) {
          ((short*)Cp)[(size_t)row * N + col] = bfbits(v);
        } else if constexpr (COUT == 2) {
          short hb = bfbits(v);
          ((short*)Cp)[(size_t)row * N + col] = hb;
          Clo[(size_t)row * N + col] = bfbits(v - bfs2f(hb));
        } else {
          ((float*)Cp)[(size_t)row * N + col] = v;
        }
      }
}

// ---------------- MFMA GEMM 256x128, 8 waves (non-split A, 2-deep) ---------
template <int CBF16, int ACT>
__global__ __launch_bounds__(512) void gemm_mfma_p256(const short* __restrict__ Ahi,
                                                      const short* __restrict__ Bthi,
                                                      const short* __restrict__ Btlo,
                                                      void* __restrict__ Cp,
                                                      const float* __restrict__ bias,
                                                      int M, int N, int K) {
  __shared__ __align__(16) short sA[2][8192];
  __shared__ __align__(16) short sB[2][8192];
  const int tid = threadIdx.x;
  const int wave = tid >> 6, lane = tid & 63;
  const int wm = wave >> 1, wn = wave & 1;
  const int nbx = gridDim.x;
  const int nwg = nbx * gridDim.y;
  const int hw = blockIdx.y * nbx + blockIdx.x;
  const int lg = (hw & 7) * (nwg >> 3) + (hw >> 3);
  const int row0 = (lg / nbx) * 256, col0 = (lg % nbx) * 128;
  const int nkb = K >> 5;
  const int ar = lane & 15, akc = lane >> 4;
  f32x4 acc[4][4] = {};

  auto stage = [&](int buf, int kb) {
    if (wave < 4) {
      const short* bh = Bthi + ((size_t)(col0 >> 7) * nkb + kb) * 4096;
      int cB = wave * 2;
      gld16(bh + (size_t)cB * 512 + lane * 8, (char*)sB[buf] + cB * 1024);
      gld16(bh + (size_t)(cB + 1) * 512 + lane * 8, (char*)sB[buf] + (cB + 1) * 1024);
    } else {
      const short* bl = Btlo + ((size_t)(col0 >> 7) * nkb + kb) * 4096;
      int cB = (wave - 4) * 2;
      gld16(bl + (size_t)cB * 512 + lane * 8, (char*)sB[buf] + 8192 + cB * 1024);
      gld16(bl + (size_t)(cB + 1) * 512 + lane * 8, (char*)sB[buf] + 8192 + (cB + 1) * 1024);
    }
    int cA = wave * 2;
    gld16(Ahi + (size_t)(row0 + cA * 16 + ar) * K + kb * 32 + akc * 8,
          (char*)sA[buf] + cA * 1024);
    gld16(Ahi + (size_t)(row0 + (cA + 1) * 16 + ar) * K + kb * 32 + akc * 8,
          (char*)sA[buf] + (cA + 1) * 1024);
  };

  stage(0, 0);
  for (int kb = 0; kb < nkb; kb++) {
    int cur = kb & 1;
    if (kb + 1 < nkb) {
      stage(cur ^ 1, kb + 1);
      asm volatile("s_waitcnt vmcnt(4)" ::: "memory");
    } else {
      asm volatile("s_waitcnt vmcnt(0)" ::: "memory");
    }
    __builtin_amdgcn_sched_barrier(0);
    __builtin_amdgcn_s_barrier();
    __builtin_amdgcn_sched_barrier(0);
    asm volatile("" ::: "memory");
    short8v af[4], bh[4], bl[4];
#pragma unroll
    for (int f = 0; f < 4; f++) {
      af[f] = *(short8v*)((char*)sA[cur] + (wm * 4 + f) * 1024 + lane * 16);
      bh[f] = *(short8v*)((char*)sB[cur] + (wn * 4 + f) * 1024 + lane * 16);
      bl[f] = *(short8v*)((char*)sB[cur] + 8192 + (wn * 4 + f) * 1024 + lane * 16);
    }
#pragma unroll
    for (int i = 0; i < 4; i++)
#pragma unroll
      for (int j = 0; j < 4; j++) {
        acc[i][j] = __builtin_amdgcn_mfma_f32_16x16x32_bf16(af[i], bh[j], acc[i][j], 0, 0, 0);
        acc[i][j] = __builtin_amdgcn_mfma_f32_16x16x32_bf16(af[i], bl[j], acc[i][j], 0, 0, 0);
      }
    asm volatile("" ::: "memory");
    __builtin_amdgcn_sched_barrier(0);
    __builtin_amdgcn_s_barrier();
    __builtin_amdgcn_sched_barrier(0);
  }
#pragma unroll
  for (int i = 0; i < 4; i++)
#pragma unroll
    for (int j = 0; j < 4; j++)
#pragma unroll
      for (int r = 0; r < 4; r++) {
        int row = row0 + wm * 64 + i * 16 + ((lane >> 4) << 2) + r;
        int col = col0 + wn * 64 + j * 16 + (lane & 15);
        float v = acc[i][j][r];
        if (bias) v += bias[col];
        if constexpr (ACT == 1) v = v > 0.0f ? v : expf(v) - 1.0f;
        if constexpr (ACT == 2) v = fmaxf(v, 0.0f);
        if constexpr (CBF16) {
          ((short*)Cp)[(size_t)row * N + col] = bfbits(v);
        } else {
          ((float*)Cp)[(size_t)row * N + col] = v;
        }
      }
}

// ---------------- GAT1 fused (rank-1) ----------------
__global__ void k_gat1_csr(const float* __restrict__ x, const float* __restrict__ wl,
                           const float* __restrict__ wr, const float* __restrict__ att,
                           const int* __restrict__ rowptr, const int* __restrict__ srck,
                           float* __restrict__ ework, const float* __restrict__ bias,
                           float* __restrict__ out) {
  int node = blockIdx.x * 4 + (threadIdx.x >> 6);
  int lane = threadIdx.x & 63;
  float wlv = wl[lane], wrv = wr[lane], av = att[lane];
  float xd = x[node];
  int beg = rowptr[node], end = rowptr[node + 1];
  float m = -INFINITY;
  for (int k = beg; k < end; k++) {
    float v = x[srck[k]] * wlv + xd * wrv;
    v = v > 0.0f ? v : 0.2f * v;
    float e = av * v;
#pragma unroll
    for (int off = 32; off; off >>= 1) e += __shfl_xor(e, off);
    if (lane == 0) ework[k] = e;
    m = fmaxf(m, e);
  }
  __syncthreads();
  float sum = 0.0f, agg = 0.0f;
  for (int k = beg + lane; k < end; k += 64) {
    float p = expf(ework[k] - m);
    sum += p;
    agg += p * x[srck[k]];
  }
#pragma unroll
  for (int off = 32; off; off >>= 1) {
    sum += __shfl_xor(sum, off);
    agg += __shfl_xor(agg, off);
  }
  float o = agg / (sum + 1e-16f) * wlv + bias[lane];
  out[(size_t)node * 64 + lane] = o > 0.0f ? o : expf(o) - 1.0f;
}

// ---------------- CSR per-node logits + softmax ----------------
template <int FO, int STR, typename XT>
__global__ void k_logits_csr(const XT* __restrict__ X, const float* __restrict__ att,
                             const int* __restrict__ rowptr, const int* __restrict__ srck,
                             float* __restrict__ pk, float* __restrict__ ssum) {
  int node = blockIdx.x * 4 + (threadIdx.x >> 6);
  int lane = threadIdx.x & 63;
  constexpr int NV = FO / 64;
  float xr[NV], at[NV];
  if constexpr (sizeof(XT) == 2) {
    const short* xrp = (const short*)X + (size_t)node * STR + FO;
#pragma unroll
    for (int j = 0; j < FO / 512; j++) {
      short8v v = *(const short8v*)(xrp + j * 512 + lane * 8);
      f32x4 a0 = *(const f32x4*)(att + j * 512 + lane * 8);
      f32x4 a1 = *(const f32x4*)(att + j * 512 + lane * 8 + 4);
#pragma unroll
      for (int t = 0; t < 8; t++) {
        xr[j * 8 + t] = bfs2f(v[t]);
        at[j * 8 + t] = t < 4 ? a0[t] : a1[t - 4];
      }
    }
  } else {
    const float* xrp = (const float*)X + (size_t)node * STR + FO;
#pragma unroll
    for (int j = 0; j < FO / 256; j++) {
      f32x4 v = *(const f32x4*)(xrp + j * 256 + lane * 4);
      f32x4 a = *(const f32x4*)(att + j * 256 + lane * 4);
#pragma unroll
      for (int t = 0; t < 4; t++) {
        xr[j * 4 + t] = v[t];
        at[j * 4 + t] = a[t];
      }
    }
  }
  int beg = rowptr[node], end = rowptr[node + 1];
  float m = -INFINITY;
  for (int k = beg; k < end; k++) {
    int s = srck[k];
    float acc = 0.0f;
    if constexpr (sizeof(XT) == 2) {
      const short* xlp = (const short*)X + (size_t)s * STR;
#pragma unroll
      for (int j = 0; j < FO / 512; j++) {
        short8v v = *(const short8v*)(xlp + j * 512 + lane * 8);
#pragma unroll
        for (int t = 0; t < 8; t++) {
          float u = bfs2f(v[t]) + xr[j * 8 + t];
          u = u > 0.0f ? u : 0.2f * u;
          acc += at[j * 8 + t] * u;
        }
      }
    } else {
      const float* xlp = (const float*)X + (size_t)s * STR;
#pragma unroll
      for (int j = 0; j < FO / 256; j++) {
        f32x4 v = *(const f32x4*)(xlp + j * 256 + lane * 4);
#pragma unroll
        for (int t = 0; t < 4; t++) {
          float u = v[t] + xr[j * 4 + t];
          u = u > 0.0f ? u : 0.2f * u;
          acc += at[j * 4 + t] * u;
        }
      }
    }
#pragma unroll
    for (int off = 32; off; off >>= 1) acc += __shfl_xor(acc, off);
    if (lane == 0) pk[k] = acc;
    m = fmaxf(m, acc);
  }
  __syncthreads();
  float sum = 0.0f;
  for (int k = beg + lane; k < end; k += 64) {
    float p = expf(pk[k] - m);
    pk[k] = p;
    sum += p;
  }
#pragma unroll
  for (int off = 32; off; off >>= 1) sum += __shfl_xor(sum, off);
  if (lane == 0) ssum[node] = sum;
}

// ---------------- gather-aggregation ----------------
template <int MODE, int SSTR, int OSTR>
__global__ void k_agg512(const float* __restrict__ Xsrc, const float* __restrict__ pk,
                         const float* __restrict__ ssum, const int* __restrict__ rowptr,
                         const int* __restrict__ srck, const float* __restrict__ normk,
                         const float* __restrict__ xwrb, const float* __restrict__ bias,
                         float* __restrict__ out, short* __restrict__ outhi,
                         short* __restrict__ outlo) {
  int wave = threadIdx.x >> 6;
  int node = blockIdx.x * 2 + (wave >> 1);
  int lane = threadIdx.x & 63;
  int c0 = (wave & 1) * 256 + lane * 4;
  f32x4 acc = {};
  int beg = rowptr[node], end = rowptr[node + 1];
  float inv = (MODE == 0) ? 1.0f / (ssum[node] + 1e-16f) : 1.0f;
  for (int k = beg; k < end; k++) {
    int s = srck[k];
    float w = (MODE == 0) ? pk[k] * inv : normk[k];
    f32x4 v = *(const f32x4*)(Xsrc + (size_t)s * SSTR + c0);
#pragma unroll
    for (int t = 0; t < 4; t++) acc[t] += w * v[t];
  }
  if constexpr (MODE == 1) {
    f32x4 xv = *(const f32x4*)(xwrb + (size_t)node * SSTR + 512 + c0);
#pragma unroll
    for (int t = 0; t < 4; t++) acc[t] = fmaxf(acc[t] + xv[t] + bias[c0 + t], 0.0f);
    *(f32x4*)(out + (size_t)node * OSTR + c0) = acc;
  } else {
    short4v hh, ll;
#pragma unroll
    for (int t = 0; t < 4; t++) {
      hh[t] = bfbits(acc[t]);
      ll[t] = bfbits(acc[t] - bfs2f(hh[t]));
    }
    *(short4v*)(outhi + (size_t)node * OSTR + c0) = hh;
    *(short4v*)(outlo + (size_t)node * OSTR + c0) = ll;
  }
}

template <int MODE, int SSTR, int XOFF>
__global__ void k_agg64(const float* __restrict__ Xsrc, const float* __restrict__ pk,
                        const float* __restrict__ ssum, const int* __restrict__ rowptr,
                        const int* __restrict__ srck, const float* __restrict__ normk,
                        const float* __restrict__ xwrb, const float* __restrict__ bias,
                        float* __restrict__ out, short* __restrict__ outhi,
                        short* __restrict__ outlo) {
  int node = blockIdx.x * (blockDim.x >> 6) + (threadIdx.x >> 6);
  if (node >= NN) return;
  int lane = threadIdx.x & 63;
  int cg = lane & 15, eg = lane >> 4;
  int c0 = cg * 4;
  f32x4 acc = {};
  int beg = rowptr[node], end = rowptr[node + 1];
  float inv = (MODE == 0) ? 1.0f / (ssum[node] + 1e-16f) : 1.0f;
  for (int k = beg + eg; k < end; k += 4) {
    int s = srck[k];
    float w = (MODE == 0) ? pk[k] * inv : normk[k];
    f32x4 v = *(const f32x4*)(Xsrc + (size_t)s * SSTR + c0);
#pragma unroll
    for (int t = 0; t < 4; t++) acc[t] += w * v[t];
  }
#pragma unroll
  for (int t = 0; t < 4; t++) {
    acc[t] += __shfl_xor(acc[t], 16);
    acc[t] += __shfl_xor(acc[t], 32);
  }
  if (eg == 0) {
    if constexpr (MODE == 1) {
      f32x4 xv = *(const f32x4*)(xwrb + (size_t)node * SSTR + XOFF + c0);
#pragma unroll
      for (int t = 0; t < 4; t++) acc[t] = fmaxf(acc[t] + xv[t] + bias[c0 + t], 0.0f);
      *(f32x4*)(out + (size_t)node * 64 + c0) = acc;
    } else {
      short4v hh, ll;
#pragma unroll
      for (int t = 0; t < 4; t++) {
        hh[t] = bfbits(acc[t]);
        ll[t] = bfbits(acc[t] - bfs2f(hh[t]));
      }
      *(short4v*)(outhi + (size_t)node * 64 + c0) = hh;
      *(short4v*)(outlo + (size_t)node * 64 + c0) = ll;
    }
  }
}

// ---------------- GraphNorm (vectorized, row-split partial stats) ----------
template <typename T, int VEC>
__global__ void k_gn_stats_v(const T* __restrict__ x, const int* __restrict__ R, int C,
                             float* __restrict__ s1p, float* __restrict__ s2p) {
  int g = blockIdx.x;
  int rs = blockIdx.y;
  int RS = gridDim.y;
  int c0 = threadIdx.x * VEC;
  if (c0 >= C) return;
  int beg = R[g], end = R[g + 1];
  int len = end - beg;
  int lo = beg + (int)(((long long)len * rs) / RS);
  int hi2 = beg + (int)(((long long)len * (rs + 1)) / RS);
  float a[VEC] = {}, b[VEC] = {};
  for (int n = lo; n < hi2; n++) {
    const T* p = x + (size_t)n * C + c0;
    float v[VEC];
    if constexpr (sizeof(T) == 2) {
      short8v h = *(const short8v*)p;
#pragma unroll
      for (int t = 0; t < VEC; t++) v[t] = bfs2f(h[t]);
    } else {
      f32x4 h = *(const f32x4*)p;
#pragma unroll
      for (int t = 0; t < VEC; t++) v[t] = h[t];
    }
#pragma unroll
    for (int t = 0; t < VEC; t++) {
      a[t] += v[t];
      b[t] += v[t] * v[t];
    }
  }
#pragma unroll
  for (int t = 0; t < VEC; t++) {
    s1p[((size_t)rs * NG + g) * C + c0 + t] = a[t];
    s2p[((size_t)rs * NG + g) * C + c0 + t] = b[t];
  }
}

// pair-plane stats: value = hi + lo (fp32-grade)
__global__ void k_gn_stats_pair(const short* __restrict__ xhi, const short* __restrict__ xlo,
                                const int* __restrict__ R, int C, float* __restrict__ s1p,
                                float* __restrict__ s2p) {
  int g = blockIdx.x;
  int rs = blockIdx.y;
  int RS = gridDim.y;
  int c0 = threadIdx.x * 8;
  if (c0 >= C) return;
  int beg = R[g], end = R[g + 1];
  int len = end - beg;
  int lo = beg + (int)(((long long)len * rs) / RS);
  int hi2 = beg + (int)(((long long)len * (rs + 1)) / RS);
  float a[8] = {}, b[8] = {};
  for (int n = lo; n < hi2; n++) {
    short8v h = *(const short8v*)(xhi + (size_t)n * C + c0);
    short8v l = *(const short8v*)(xlo + (size_t)n * C + c0);
#pragma unroll
    for (int t = 0; t < 8; t++) {
      float v = bfs2f(h[t]) + bfs2f(l[t]);
      a[t] += v;
      b[t] += v * v;
    }
  }
#pragma unroll
  for (int t = 0; t < 8; t++) {
    s1p[((size_t)rs * NG + g) * C + c0 + t] = a[t];
    s2p[((size_t)rs * NG + g) * C + c0 + t] = b[t];
  }
}

// ---------------- GN coefficient precompute: scale/shift per (g,c) --------
__global__ void k_gn_coef(const float* __restrict__ s1p, const float* __restrict__ s2p,
                          const float* __restrict__ cnt, const float* __restrict__ w,
                          const float* __restrict__ b, const float* __restrict__ ms, int C,
                          float* __restrict__ cs, float* __restrict__ cb) {
  int i = blockIdx.x * blockDim.x + threadIdx.x;
  if (i >= NG * C) return;
  int g = i / C, c = i % C;
  float sv1 = 0.0f, sv2 = 0.0f;
#pragma unroll
  for (int rs = 0; rs < 4; rs++) {
    sv1 += s1p[((size_t)rs * NG + g) * C + c];
    sv2 += s2p[((size_t)rs * NG + g) * C + c];
  }
  float ct = cnt[g];
  float mean = sv1 / ct;
  float mm = mean * ms[c];
  float var = sv2 / ct - 2.0f * mm * mean + mm * mm;
  float inv = 1.0f / sqrtf(var + 1e-5f);
  float sc = inv * w[c];
  cs[i] = sc;
  cb[i] = b[c] - mm * sc;
}

// pair-plane apply (coef): read hi+lo, affine in fp32, write back hi+lo
__global__ void k_gn_apply_pair(short* __restrict__ xhi, short* __restrict__ xlo,
                                const int* __restrict__ batch,
                                const float* __restrict__ cs, const float* __restrict__ cb,
                                int C, int total_vec) {
  int i = blockIdx.x * blockDim.x + threadIdx.x;
  if (i >= total_vec) return;
  int cpv = C / 8;
  int n = i / cpv, c0 = (i % cpv) * 8;
  int g = batch[n];
  short8v h = *(const short8v*)(xhi + (size_t)n * C + c0);
  short8v l = *(const short8v*)(xlo + (size_t)n * C + c0);
  short8v ho, loo;
#pragma unroll
  for (int t = 0; t < 8; t++) {
    int cc = c0 + t;
    float v = bfs2f(h[t]) + bfs2f(l[t]);
    v = v * cs[(size_t)g * C + cc] + cb[(size_t)g * C + cc];
    short hb = bfbits(v);
    ho[t] = hb;
    loo[t] = bfbits(v - bfs2f(hb));
  }
  *(short8v*)(xhi + (size_t)n * C + c0) = ho;
  *(short8v*)(xlo + (size_t)n * C + c0) = loo;
}

// EMIT: 0 in-place only; 2 = + hi plane; 3 = + hi & lo planes (VEC=4)
template <typename T, int VEC, int EMIT>
__global__ void k_gn_apply_v(T* __restrict__ x, const int* __restrict__ batch,
                             const float* __restrict__ cs, const float* __restrict__ cb,
                             int C, int total_vec, short* __restrict__ hip,
                             short* __restrict__ lop) {
  int i = blockIdx.x * blockDim.x + threadIdx.x;
  if (i >= total_vec) return;
  int cpv = C / VEC;
  int n = i / cpv, c0 = (i % cpv) * VEC;
  int g = batch[n];
  T* p = x + (size_t)n * C + c0;
  float v[VEC];
  if constexpr (sizeof(T) == 2) {
    short8v h = *(const short8v*)p;
#pragma unroll
    for (int t = 0; t < VEC; t++) v[t] = bfs2f(h[t]);
  } else {
    f32x4 h = *(const f32x4*)p;
#pragma unroll
    for (int t = 0; t < VEC; t++) v[t] = h[t];
  }
#pragma unroll
  for (int t = 0; t < VEC; t++) {
    int cc = c0 + t;
    v[t] = v[t] * cs[(size_t)g * C + cc] + cb[(size_t)g * C + cc];
  }
  if constexpr (sizeof(T) == 2) {
    short8v h;
#pragma unroll
    for (int t = 0; t < VEC; t++) h[t] = bfbits(v[t]);
    *(short8v*)p = h;
  } else {
    f32x4 h;
#pragma unroll
    for (int t = 0; t < VEC; t++) h[t] = v[t];
    *(f32x4*)p = h;
  }
  if constexpr (EMIT == 2 || EMIT == 3) {
    short4v hh;
#pragma unroll
    for (int t = 0; t < VEC; t++) hh[t] = bfbits(v[t]);
    *(short4v*)(hip + (size_t)n * C + c0) = hh;
    if constexpr (EMIT == 3) {
      short4v ll;
#pragma unroll
      for (int t = 0; t < VEC; t++) ll[t] = bfbits(v[t] - bfs2f(hh[t]));
      *(short4v*)(lop + (size_t)n * C + c0) = ll;
    }
  }
}

// ---------------- pooling + final linear ----------------
__global__ void k_pool(const float* __restrict__ h, const int* __restrict__ R,
                       const float* __restrict__ cnt, const float* __restrict__ lw,
                       const float* __restrict__ lb, float* __restrict__ out) {
  int g = blockIdx.x;
  int c = threadIdx.x;  // 64
  int beg = R[g], end = R[g + 1];
  float mx = -INFINITY, sm = 0.0f;
  for (int n = beg; n < end; n++) {
    float v = h[(size_t)n * 64 + c];
    mx = fmaxf(mx, v);
    sm += v;
  }
  __shared__ float feat[192];
  feat[c] = mx;
  feat[64 + c] = sm / cnt[g];
  feat[128 + c] = sm;
  __syncthreads();
  if (c < 2) {
    float acc = lb[c];
    for (int j = 0; j < 192; j++) acc += feat[j] * lw[j * 2 + c];
    out[g * 2 + c] = acc;
  }
}

// ---------------- launch ----------------

extern "C" void kernel_launch(void* const* d_in, const int* in_sizes, int n_in,
                              void* d_out, int out_size, void* d_ws, size_t ws_size,
                              hipStream_t stream) {
  const float* x = (const float*)d_in[0];
  const int* ei = (const int*)d_in[1];
  const int* batch = (const int*)d_in[2];
  const float* g1wl = (const float*)d_in[3];
  const float* g1wr = (const float*)d_in[4];
  const float* g1att = (const float*)d_in[5];
  const float* g1b = (const float*)d_in[6];
  const float* g2wl = (const float*)d_in[7];
  const float* g2wr = (const float*)d_in[8];
  const float* g2att = (const float*)d_in[9];
  const float* g2b = (const float*)d_in[10];
  const float* g3wl = (const float*)d_in[11];
  const float* g3wr = (const float*)d_in[12];
  const float* g3att = (const float*)d_in[13];
  const float* g3b = (const float*)d_in[14];
  const float* gn1w = (const float*)d_in[15];
  const float* gn1b = (const float*)d_in[16];
  const float* gn1ms = (const float*)d_in[17];
  const float* gn2w = (const float*)d_in[18];
  const float* gn2b = (const float*)d_in[19];
  const float* gn2ms = (const float*)d_in[20];
  const float* gn3w = (const float*)d_in[21];
  const float* gn3b = (const float*)d_in[22];
  const float* gn3ms = (const float*)d_in[23];
  const float* gn4w = (const float*)d_in[24];
  const float* gn4b = (const float*)d_in[25];
  const float* gn4ms = (const float*)d_in[26];
  const float* gn5w = (const float*)d_in[27];
  const float* gn5b = (const float*)d_in[28];
  const float* gn5ms = (const float*)d_in[29];
  const float* a1wi = (const float*)d_in[30];
  const float* a1wr = (const float*)d_in[31];
  const float* a1b = (const float*)d_in[32];
  const float* a2wi = (const float*)d_in[33];
  const float* a2wr = (const float*)d_in[34];
  const float* a2b = (const float*)d_in[35];
  const float* linw = (const float*)d_in[36];
  const float* linb = (const float*)d_in[37];
  const int* srcp = ei;
  const int* dstp = ei + NE;
  float* out = (float*)d_out;

  float* ws = (float*)d_ws;
  size_t o = 0;
  auto alloc = [&](size_t nfloats) { float* p = ws + o; o += nfloats; return p; };
  float* BIG0f = alloc((size_t)NN * 1024);  // 64 MB
  float* BIG1f = alloc((size_t)NN * 1024);  // 64 MB
  float* B0 = alloc((size_t)NN * 512);      // 32 MB
  float* B1 = alloc((size_t)NN * 512);      // 32 MB
  float* h1 = alloc((size_t)NN * 64);
  float* S0 = alloc((size_t)NN * 64);
  float* S1 = alloc((size_t)NN * 64);
  float* S2 = alloc((size_t)NN * 64);
  float* pk = alloc(NESL);
  float* normk = alloc(NESL);
  float* ssum = alloc(NN);
  float* dis = alloc(NN);
  float* cnt = alloc(NG);
  float* s1 = alloc((size_t)4 * NG * 2048);
  float* s2 = alloc((size_t)4 * NG * 2048);
  float* coefS = alloc((size_t)NG * 2048);
  float* coefB = alloc((size_t)NG * 2048);
  short* WThi = (short*)alloc((size_t)4096 * 512 / 2);
  short* WTlo = (short*)alloc((size_t)4096 * 512 / 2);
  int* deg = (int*)alloc(NN);
  int* rowptr = (int*)alloc(NN + 1);
  int* fill = (int*)alloc(NN);
  int* srck = (int*)alloc(NESL);
  int* R = (int*)alloc(72);

  bf16* XLR3 = (bf16*)BIG0f;       // [NN][4096] bf16 (spans BIG0f+BIG1f)
  short* h3hi = (short*)BIG0f;     // [NN][2048] hi plane (after XLR3 dead)
  short* h3lo = (short*)BIG1f;     // [NN][2048] lo plane
  float* h4 = BIG1f;               // [NN][512] f32 (after ARMA1 GEMM consumed h3lo)
  short* h4hi = (short*)BIG0f;     // [NN][512] planes (after h3hi dead)
  short* h4lo = h4hi + (size_t)NN * 512;
  short* XLR2 = (short*)B0;        // [NN][1024] bf16
  float* h2 = B0;                  // [NN][512] f32 (after XLR2 dead)
  short* h2hi = (short*)B1;        // [NN][512] bf16 hi plane
  short* agg2hi = (short*)B1;      // [NN][512] planes (after h2hi dead)
  short* agg2lo = agg2hi + (size_t)NN * 512;
  float* TXW1 = B0;                // [t1|xwr1] [NN][1024] f32 (spans B0+B1)
  float* TXW2 = S0;                // [t2|xwr2] [NN][128] f32 (spans S0+S1)
  short* h1hi = (short*)S2;        // [NN][64] planes
  short* h1lo = h1hi + (size_t)NN * 64;
  short* aggShi = (short*)S0;      // [NN][64] planes
  short* aggSlo = aggShi + (size_t)NN * 64;
  float* h5 = S2;                  // [NN][64] f32 (after h1 planes dead)

  // ---- preprocessing ----
  k_zero2<<<NN / 256, 256, 0, stream>>>(deg, fill, NN);
  k_ranges<<<1, 128, 0, stream>>>(batch, R, cnt);
  k_deg<<<NE / 256, 256, 0, stream>>>(dstp, deg);
  k_scan<<<1, 1024, 0, stream>>>(deg, rowptr);
  k_dis<<<NN / 256, 256, 0, stream>>>(deg, dis);
  k_fill<<<(NESL + 255) / 256, 256, 0, stream>>>(srcp, dstp, rowptr, dis, fill, srck, normk);

  // ---- GAT1 (1 -> 64, rank-1, fused) ----
  k_gat1_csr<<<NN / 4, 256, 0, stream>>>(x, g1wl, g1wr, g1att, rowptr, srck, pk, g1b, h1);
  k_gn_stats_v<float, 4><<<dim3(NG, 4), 16, 0, stream>>>(h1, R, 64, s1, s2);
  k_gn_coef<<<(NG * 64 + 255) / 256, 256, 0, stream>>>(s1, s2, cnt, gn1w, gn1b, gn1ms, 64,
                                                       coefS, coefB);
  k_gn_apply_v<float, 4, 3><<<NN * 16 / 256, 256, 0, stream>>>(h1, batch, coefS, coefB, 64,
                                                               NN * 16, h1hi, h1lo);

  // ---- GAT2 (64 -> 512) ----
  k_wsplit2<<<8192 / 256, 256, 0, stream>>>(g2wl, g2wr, WThi, WTlo, 64, 512);
  gemm_mfma_p<1, 1, 0><<<dim3(8, 128), 256, 0, stream>>>(h1hi, h1lo, WThi, WTlo, XLR2, nullptr,
                                                         nullptr, NN, 1024, 64);
  k_logits_csr<512, 1024, bf16><<<NN / 4, 256, 0, stream>>>((const bf16*)XLR2, g2att, rowptr,
                                                            srck, pk, ssum);
  k_agg64<0, 64, 0><<<NN / 4, 256, 0, stream>>>(h1, pk, ssum, rowptr, srck, normk, nullptr,
                                                nullptr, nullptr, aggShi, aggSlo);
  gemm_mfma_p<1, 0, 1><<<dim3(4, 128), 256, 0, stream>>>(aggShi, aggSlo, WThi, WTlo, h2,
                                                         nullptr, g2b, NN, 512, 64);
  k_gn_stats_v<float, 4><<<dim3(NG, 4), 128, 0, stream>>>(h2, R, 512, s1, s2);
  k_gn_coef<<<(NG * 512 + 255) / 256, 256, 0, stream>>>(s1, s2, cnt, gn2w, gn2b, gn2ms, 512,
                                                        coefS, coefB);
  k_gn_apply_v<float, 4, 2><<<NN * 128 / 256, 256, 0, stream>>>(h2, batch, coefS, coefB, 512,
                                                                NN * 128, h2hi, nullptr);

  // ---- GAT3 (512 -> 2048) ----
  k_wsplit2<<<262144 / 256, 256, 0, stream>>>(g3wl, g3wr, WThi, WTlo, 512, 2048);
  gemm_mfma_p256<1, 0><<<dim3(32, 64), 512, 0, stream>>>(h2hi, WThi, WTlo, XLR3, nullptr, NN,
                                                         4096, 512);
  k_logits_csr<2048, 4096, bf16><<<NN / 4, 256, 0, stream>>>(XLR3, g3att, rowptr, srck, pk, ssum);
  k_agg512<0, 512, 512><<<NN / 2, 256, 0, stream>>>(h2, pk, ssum, rowptr, srck, normk, nullptr,
                                                    nullptr, nullptr, agg2hi, agg2lo);
  gemm_mfma_p<1, 2, 1><<<dim3(16, 128), 256, 0, stream>>>(agg2hi, agg2lo, WThi, WTlo, h3hi,
                                                          h3lo, g3b, NN, 2048, 512);
  k_gn_stats_pair<<<dim3(NG, 4), 256, 0, stream>>>(h3hi, h3lo, R, 2048, s1, s2);
  k_gn_coef<<<(NG * 2048 + 255) / 256, 256, 0, stream>>>(s1, s2, cnt, gn3w, gn3b, gn3ms, 2048,
                                                         coefS, coefB);
  k_gn_apply_pair<<<NN * 256 / 256, 256, 0, stream>>>(h3hi, h3lo, batch, coefS, coefB, 2048,
                                                      NN * 256);

  // ---- ARMA1 (2048 -> 512): SPLITA fp32-grade (h3 hi + lo planes) ----
  k_wsplit2<<<262144 / 256, 256, 0, stream>>>(a1wi, a1wr, WThi, WTlo, 2048, 512);
  gemm_mfma_p<1, 0, 0><<<dim3(8, 128), 256, 0, stream>>>(h3hi, h3lo, WThi, WTlo, TXW1, nullptr,
                                                         nullptr, NN, 1024, 2048);
  k_agg512<1, 1024, 512><<<NN / 2, 256, 0, stream>>>(TXW1, pk, nullptr, rowptr, srck, normk,
                                                     TXW1, a1b, h4, nullptr, nullptr);
  k_gn_stats_v<float, 4><<<dim3(NG, 4), 128, 0, stream>>>(h4, R, 512, s1, s2);
  k_gn_coef<<<(NG * 512 + 255) / 256, 256, 0, stream>>>(s1, s2, cnt, gn4w, gn4b, gn4ms, 512,
                                                        coefS, coefB);
  k_gn_apply_v<float, 4, 3><<<NN * 128 / 256, 256, 0, stream>>>(h4, batch, coefS, coefB, 512,
                                                                NN * 128, h4hi, h4lo);

  // ---- ARMA2 (512 -> 64) ----
  k_wsplit2<<<8192 / 256, 256, 0, stream>>>(a2wi, a2wr, WThi, WTlo, 512, 64);
  gemm_mfma_p<1, 0, 0><<<dim3(1, 128), 256, 0, stream>>>(h4hi, h4lo, WThi, WTlo, TXW2, nullptr,
                                                         nullptr, NN, 128, 512);
  k_agg64<1, 128, 64><<<NN / 4, 256, 0, stream>>>(TXW2, pk, nullptr, rowptr, srck, normk, TXW2,
                                                  a2b, h5, nullptr, nullptr);
  k_gn_stats_v<float, 4><<<dim3(NG, 4), 16, 0, stream>>>(h5, R, 64, s1, s2);
  k_gn_coef<<<(NG * 64 + 255) / 256, 256, 0, stream>>>(s1, s2, cnt, gn5w, gn5b, gn5ms, 64,
                                                       coefS, coefB);
  k_gn_apply_v<float, 4, 0><<<NN * 16 / 256, 256, 0, stream>>>(h5, batch, coefS, coefB, 64,
                                                               NN * 16, nullptr, nullptr);

  // ---- pooling + linear ----
  k_pool<<<NG, 64, 0, stream>>>(h5, R, cnt, linw, linb, out);
}